// Round 1
// baseline (6138.227 us; speedup 1.0000x reference)
//
#include <hip/hip_runtime.h>

// ---------------- problem constants ----------------
static const int N_ROWS = 65536;
static const int E_DIM  = 512;
static const int N_E    = 1024;
static const int NUM_Q  = 4;

// d_out layout (fp32 elements)
static const size_t XQ_OFF   = 0;
static const size_t LOSS_OFF = (size_t)N_ROWS * E_DIM;          // 33554432
static const size_t IDX_OFF  = LOSS_OFF + 1;                    // 33554433
static const size_t DIST_OFF = IDX_OFF + (size_t)N_ROWS * NUM_Q;// 33816577

// ws layout (bytes)
static const size_t WS_RNORM = 0;                                // N floats
static const size_t WS_IDX   = 262144;                           // 4*N ints
static const size_t WS_ENORM = 1310720;                          // 4096 floats
static const size_t WS_LPART = 1327104;                          // 4*16384 doubles

#define BK 16
#define LDSS 132   // padded LDS row stride (floats): breaks pow2 bank patterns

// ---------------- ||e||^2 for all 4096 codewords ----------------
__global__ __launch_bounds__(256) void enorm_kernel(const float* __restrict__ cb,
                                                    float* __restrict__ enorm) {
    const int lane = threadIdx.x & 63;
    const int wave = threadIdx.x >> 6;
    const int row  = blockIdx.x * 4 + wave;     // 0..4095
    const float* p = cb + (size_t)row * E_DIM + lane * 8;
    float4 v0 = *(const float4*)p;
    float4 v1 = *(const float4*)(p + 4);
    float s = v0.x*v0.x + v0.y*v0.y + v0.z*v0.z + v0.w*v0.w
            + v1.x*v1.x + v1.y*v1.y + v1.z*v1.z + v1.w*v1.w;
    for (int off = 32; off; off >>= 1) s += __shfl_down(s, off);
    if (lane == 0) enorm[row] = s;
}

// ---------------- ||x||^2 per row ----------------
__global__ __launch_bounds__(256) void rnorm_kernel(const float* __restrict__ x,
                                                    float* __restrict__ rnorm) {
    const int lane = threadIdx.x & 63;
    const int wave = threadIdx.x >> 6;
    const size_t row = (size_t)blockIdx.x * 4 + wave;
    const float* p = x + row * E_DIM + lane * 8;
    float4 v0 = *(const float4*)p;
    float4 v1 = *(const float4*)(p + 4);
    float s = v0.x*v0.x + v0.y*v0.y + v0.z*v0.z + v0.w*v0.w
            + v1.x*v1.x + v1.y*v1.y + v1.z*v1.z + v1.w*v1.w;
    for (int off = 32; off; off >>= 1) s += __shfl_down(s, off);
    if (lane == 0) rnorm[row] = s;
}

// ---------------- distance GEMM: D = (rnorm - 2*A.B^T) + enorm ----------------
// 128x128 tile, 8x8 microtile (split 4+4), two-level fp32 accumulation.
__global__ __launch_bounds__(256, 2) void gemm_dist_kernel(
    const float* __restrict__ A,      // [N_ROWS, 512] residual (or x)
    const float* __restrict__ B,      // [1024, 512] codebook for this stage
    const float* __restrict__ rnorm,  // [N_ROWS]
    const float* __restrict__ enorm,  // [1024] this stage
    float* __restrict__ dist)         // d_out + DIST_OFF + q*N_E  (row stride 4096)
{
    __shared__ __align__(16) float As[BK * LDSS];
    __shared__ __align__(16) float Bs[BK * LDSS];

    const int tid = threadIdx.x;
    const int rowBase = blockIdx.y * 128;
    const int colBase = blockIdx.x * 128;

    // staging: thread -> (row lm, k-offset lk), 2x float4 per matrix
    const int lm = tid >> 1;
    const int lk = (tid & 1) * 8;
    const float* aP = A + (size_t)(rowBase + lm) * E_DIM + lk;
    const float* bP = B + (size_t)(colBase + lm) * E_DIM + lk;

    // compute: 16x16 thread grid, each 4+4 rows x 4+4 cols
    const int tx = tid & 15;
    const int ty = tid >> 4;
    const int c0 = tx * 4;
    const int r0 = ty * 4;

    float lo[8][8];
    float hi[8][8];
#pragma unroll
    for (int i = 0; i < 8; ++i)
#pragma unroll
        for (int j = 0; j < 8; ++j) { lo[i][j] = 0.f; hi[i][j] = 0.f; }

    for (int k0 = 0; k0 < E_DIM; k0 += BK) {
        float4 av0 = *(const float4*)(aP + k0);
        float4 av1 = *(const float4*)(aP + k0 + 4);
        float4 bv0 = *(const float4*)(bP + k0);
        float4 bv1 = *(const float4*)(bP + k0 + 4);
        __syncthreads();   // previous iter's reads done
        As[(lk+0)*LDSS + lm] = av0.x;  As[(lk+1)*LDSS + lm] = av0.y;
        As[(lk+2)*LDSS + lm] = av0.z;  As[(lk+3)*LDSS + lm] = av0.w;
        As[(lk+4)*LDSS + lm] = av1.x;  As[(lk+5)*LDSS + lm] = av1.y;
        As[(lk+6)*LDSS + lm] = av1.z;  As[(lk+7)*LDSS + lm] = av1.w;
        Bs[(lk+0)*LDSS + lm] = bv0.x;  Bs[(lk+1)*LDSS + lm] = bv0.y;
        Bs[(lk+2)*LDSS + lm] = bv0.z;  Bs[(lk+3)*LDSS + lm] = bv0.w;
        Bs[(lk+4)*LDSS + lm] = bv1.x;  Bs[(lk+5)*LDSS + lm] = bv1.y;
        Bs[(lk+6)*LDSS + lm] = bv1.z;  Bs[(lk+7)*LDSS + lm] = bv1.w;
        __syncthreads();
#pragma unroll
        for (int kk = 0; kk < BK; ++kk) {
            const float* as = &As[kk * LDSS];
            const float* bs = &Bs[kk * LDSS];
            float4 a0 = *(const float4*)(as + r0);
            float4 a1 = *(const float4*)(as + r0 + 64);
            float4 b0 = *(const float4*)(bs + c0);
            float4 b1 = *(const float4*)(bs + c0 + 64);
            float aa[8] = {a0.x,a0.y,a0.z,a0.w,a1.x,a1.y,a1.z,a1.w};
            float bb[8] = {b0.x,b0.y,b0.z,b0.w,b1.x,b1.y,b1.z,b1.w};
#pragma unroll
            for (int i = 0; i < 8; ++i)
#pragma unroll
                for (int j = 0; j < 8; ++j)
                    lo[i][j] += aa[i] * bb[j];
        }
        // merge chunk accumulator every 8 iterations (128 K) -> lower rounding error
        if (((k0 >> 4) & 7) == 7) {
#pragma unroll
            for (int i = 0; i < 8; ++i)
#pragma unroll
                for (int j = 0; j < 8; ++j) { hi[i][j] += lo[i][j]; lo[i][j] = 0.f; }
        }
    }

    // epilogue: d = fl(fl(rnorm - 2*dot) + enorm)  (matches np op order)
    float en[8];
#pragma unroll
    for (int j = 0; j < 8; ++j)
        en[j] = enorm[colBase + c0 + (j & 3) + (j >> 2) * 64];
#pragma unroll
    for (int i = 0; i < 8; ++i) {
        const int grow = rowBase + r0 + (i & 3) + (i >> 2) * 64;
        const float rn = rnorm[grow];
        float* dRow = dist + (size_t)grow * (NUM_Q * N_E);
#pragma unroll
        for (int j = 0; j < 8; ++j) {
            const int gcol = colBase + c0 + (j & 3) + (j >> 2) * 64;
            dRow[gcol] = (rn - 2.0f * hi[i][j]) + en[j];
        }
    }
}

// ---------------- argmin per row (np semantics: first min wins) ----------------
__global__ __launch_bounds__(256) void argmin_kernel(const float* __restrict__ dist,
                                                     int* __restrict__ idx_ws,
                                                     float* __restrict__ idx_out) {
    const int lane = threadIdx.x & 63;
    const int wave = threadIdx.x >> 6;
    const size_t row = (size_t)blockIdx.x * 4 + wave;
    const float* dr = dist + row * (NUM_Q * N_E);
    float best = 3.402823466e38f;
    int bi = 0;
#pragma unroll
    for (int t = 0; t < 16; ++t) {
        const int k = lane + t * 64;
        const float v = dr[k];
        if (v < best) { best = v; bi = k; }
    }
    for (int off = 32; off; off >>= 1) {
        const float ov = __shfl_down(best, off);
        const int   oi = __shfl_down(bi, off);
        if (ov < best || (ov == best && oi < bi)) { best = ov; bi = oi; }
    }
    if (lane == 0) {
        idx_ws[row] = bi;
        idx_out[row * NUM_Q] = (float)bi;
    }
}

// ---------------- residual update + loss partials ----------------
__global__ __launch_bounds__(256) void update_kernel(
    const float* __restrict__ rin, float* __restrict__ rout,
    const float* __restrict__ cb, const int* __restrict__ idxs,
    float* __restrict__ rnorm_out, double* __restrict__ lpart)
{
    __shared__ double wsum[4];
    const int lane = threadIdx.x & 63;
    const int wave = threadIdx.x >> 6;
    const size_t row = (size_t)blockIdx.x * 4 + wave;
    const int idx = idxs[row];
    const float* rp = rin + row * E_DIM + lane * 8;
    const float* gp = cb + (size_t)idx * E_DIM + lane * 8;
    float4 r0 = *(const float4*)rp,     r1 = *(const float4*)(rp + 4);
    float4 g0 = *(const float4*)gp,     g1 = *(const float4*)(gp + 4);

    float rr[8] = {r0.x,r0.y,r0.z,r0.w,r1.x,r1.y,r1.z,r1.w};
    float gg[8] = {g0.x,g0.y,g0.z,g0.w,g1.x,g1.y,g1.z,g1.w};
    float rn2[8];
    float nrm = 0.f;
    double ls = 0.0;
#pragma unroll
    for (int e = 0; e < 8; ++e) {
        const float t = gg[e] - rr[e];     // xq - r
        const float s = rr[e] + t;         // straight-through xq_st
        rn2[e] = rr[e] - s;                // new residual (exact ref op order)
        const float tsq = t * t;
        ls += (double)tsq;
        nrm += rn2[e] * rn2[e];
    }
    float4 o0 = make_float4(rn2[0], rn2[1], rn2[2], rn2[3]);
    float4 o1 = make_float4(rn2[4], rn2[5], rn2[6], rn2[7]);
    *(float4*)(rout + row * E_DIM + lane * 8)     = o0;
    *(float4*)(rout + row * E_DIM + lane * 8 + 4) = o1;

    for (int off = 32; off; off >>= 1) {
        nrm += __shfl_down(nrm, off);
        ls  += __shfl_down(ls, off);
    }
    if (lane == 0) {
        rnorm_out[row] = nrm;
        wsum[wave] = ls;
    }
    __syncthreads();
    if (threadIdx.x == 0)
        lpart[blockIdx.x] = ((wsum[0] + wsum[1]) + wsum[2]) + wsum[3];
}

// ---------------- final x_q reconstruction (exact fl-chain replay) ----------------
__global__ __launch_bounds__(256) void xq_final_kernel(
    const float* __restrict__ x, const float* __restrict__ codebooks,
    const int* __restrict__ idxs, float* __restrict__ xq_out)
{
    const int lane = threadIdx.x & 63;
    const int wave = threadIdx.x >> 6;
    const size_t row = (size_t)blockIdx.x * 4 + wave;
    const float* xp = x + row * E_DIM + lane * 8;
    float4 r0 = *(const float4*)xp, r1 = *(const float4*)(xp + 4);
    float rr[8] = {r0.x,r0.y,r0.z,r0.w,r1.x,r1.y,r1.z,r1.w};
    float acc[8];

    // prefetch all 4 gather addresses (independent loads)
    int id[NUM_Q];
#pragma unroll
    for (int q = 0; q < NUM_Q; ++q) id[q] = idxs[(size_t)q * N_ROWS + row];

#pragma unroll
    for (int q = 0; q < NUM_Q; ++q) {
        const float* gp = codebooks + ((size_t)q * N_E + id[q]) * E_DIM + lane * 8;
        float4 g0 = *(const float4*)gp, g1 = *(const float4*)(gp + 4);
        float gg[8] = {g0.x,g0.y,g0.z,g0.w,g1.x,g1.y,g1.z,g1.w};
#pragma unroll
        for (int e = 0; e < 8; ++e) {
            const float t = gg[e] - rr[e];
            const float s = rr[e] + t;
            rr[e] = rr[e] - s;
            acc[e] = (q == 0) ? s : (acc[e] + s);   // x_q = x_q + xq_st, in order
        }
    }
    float4 o0 = make_float4(acc[0], acc[1], acc[2], acc[3]);
    float4 o1 = make_float4(acc[4], acc[5], acc[6], acc[7]);
    *(float4*)(xq_out + row * E_DIM + lane * 8)     = o0;
    *(float4*)(xq_out + row * E_DIM + lane * 8 + 4) = o1;
}

// ---------------- loss reduction + final scalar ----------------
__global__ __launch_bounds__(256) void loss_final_kernel(const double* __restrict__ lpart,
                                                         float* __restrict__ out) {
    __shared__ double red[256];
    const int tid = threadIdx.x;
    float l0 = 0.f, l1 = 0.f, l2 = 0.f, l3 = 0.f;
    for (int q = 0; q < NUM_Q; ++q) {
        double s = 0.0;
        for (int i = tid; i < 16384; i += 256) s += lpart[(size_t)q * 16384 + i];
        red[tid] = s;
        __syncthreads();
        for (int st = 128; st; st >>= 1) {
            if (tid < st) red[tid] += red[tid + st];
            __syncthreads();
        }
        if (tid == 0) {
            const float m = (float)(red[0] * (1.0 / 33554432.0));  // exact /2^25
            const float l = m + 0.25f * m;  // codebook + MU*commitment
            if (q == 0) l0 = l; else if (q == 1) l1 = l; else if (q == 2) l2 = l; else l3 = l;
        }
        __syncthreads();
    }
    if (tid == 0) out[0] = (((l0 + l1) + l2) + l3) * 0.25f;
}

// ---------------- launch ----------------
extern "C" void kernel_launch(void* const* d_in, const int* in_sizes, int n_in,
                              void* d_out, int out_size, void* d_ws, size_t ws_size,
                              hipStream_t stream) {
    const float* x         = (const float*)d_in[0];
    const float* codebooks = (const float*)d_in[1];
    float* out = (float*)d_out;

    float* xq_region = out + XQ_OFF;    // doubles as residual storage during stages
    float* loss_out  = out + LOSS_OFF;
    float* idx_out   = out + IDX_OFF;
    float* dist_out  = out + DIST_OFF;

    char* ws = (char*)d_ws;
    float*  rnorm = (float*)(ws + WS_RNORM);
    int*    idxs  = (int*)(ws + WS_IDX);
    float*  enorm = (float*)(ws + WS_ENORM);
    double* lpart = (double*)(ws + WS_LPART);

    enorm_kernel<<<1024, 256, 0, stream>>>(codebooks, enorm);
    rnorm_kernel<<<16384, 256, 0, stream>>>(x, rnorm);

    for (int q = 0; q < NUM_Q; ++q) {
        const float* A = (q == 0) ? x : xq_region;
        const float* B = codebooks + (size_t)q * N_E * E_DIM;
        gemm_dist_kernel<<<dim3(8, 512), 256, 0, stream>>>(
            A, B, rnorm, enorm + (size_t)q * N_E, dist_out + (size_t)q * N_E);
        argmin_kernel<<<16384, 256, 0, stream>>>(
            dist_out + (size_t)q * N_E, idxs + (size_t)q * N_ROWS, idx_out + q);
        update_kernel<<<16384, 256, 0, stream>>>(
            A, xq_region, B, idxs + (size_t)q * N_ROWS, rnorm, lpart + (size_t)q * 16384);
    }

    xq_final_kernel<<<16384, 256, 0, stream>>>(x, codebooks, idxs, xq_region);
    loss_final_kernel<<<1, 256, 0, stream>>>(lpart, loss_out);
}